// Round 12
// baseline (183.492 us; speedup 1.0000x reference)
//
#include <hip/hip_runtime.h>
#include <math.h>

#define DM   1024
#define TTOK 2048
#define NTOK 4096   // B*T

typedef __bf16 bf16x8 __attribute__((ext_vector_type(8)));
typedef __bf16 bf16x4 __attribute__((ext_vector_type(4)));
typedef __bf16 bf16x2 __attribute__((ext_vector_type(2)));
typedef float  f32x4  __attribute__((ext_vector_type(4)));
typedef float  f32x16 __attribute__((ext_vector_type(16)));

// Q pre-scale: sm_scale (1/8) * log2(e)  -> allows p = exp2(s)
#define QSCALE 0.18033688011112042f

#if defined(__has_builtin)
#if __has_builtin(__builtin_amdgcn_exp2f)
#define EXP2F(x) __builtin_amdgcn_exp2f(x)
#endif
#endif
#ifndef EXP2F
#define EXP2F(x) exp2f(x)
#endif

#define GLDS16(g, l) __builtin_amdgcn_global_load_lds( \
    (__attribute__((address_space(1))) void*)(g),      \
    (__attribute__((address_space(3))) void*)(l), 16, 0, 0)

// counted-vmcnt barrier (T4): wait for all but N outstanding VMEM ops,
// drain LDS-op queue (lgkmcnt(0) — REQUIRED: R10's race was the missing
// lgkmcnt; a wave could cross the barrier with ds_reads still queued and
// another wave's global_load_lds overwrote the buffer), then barrier.
// VMEM never drains to 0 in the main loop.
#define WB(N) asm volatile("s_waitcnt vmcnt(" #N ") lgkmcnt(0)\n\ts_barrier" ::: "memory")

// pack two f32 -> one dword of 2 bf16 (RNE, same rounding as (__bf16) cast)
__device__ __forceinline__ unsigned pk2(float a, float b) {
    bf16x2 t; t[0] = (__bf16)a; t[1] = (__bf16)b;
    return __builtin_bit_cast(unsigned, t);
}
union FU { unsigned u[4]; bf16x8 v; };

// ---------------- fp32 -> bf16 convert: x + 4 weights in ONE launch ----------------
__global__ __launch_bounds__(256)
void cvt_all(const float* __restrict__ x,  const float* __restrict__ Wq,
             const float* __restrict__ Wk, const float* __restrict__ Wv,
             const float* __restrict__ Wo, __bf16* __restrict__ dst) {
    size_t g = ((size_t)blockIdx.x * 256 + threadIdx.x) * 8;
    const float* s;
    size_t off;
    const size_t NX = (size_t)NTOK * DM;   // 4M
    if (g < NX) { s = x; off = g; }
    else {
        size_t gg = g - NX;
        int w = (int)(gg >> 20);           // 1M-element segments
        off = gg & ((1u << 20) - 1);
        s = (w == 0) ? Wq : (w == 1) ? Wk : (w == 2) ? Wv : Wo;
    }
    float4 a = *(const float4*)(s + off);
    float4 b = *(const float4*)(s + off + 4);
    bf16x8 v;
    v[0] = (__bf16)a.x; v[1] = (__bf16)a.y; v[2] = (__bf16)a.z; v[3] = (__bf16)a.w;
    v[4] = (__bf16)b.x; v[5] = (__bf16)b.y; v[6] = (__bf16)b.z; v[7] = (__bf16)b.w;
    *(bf16x8*)(dst + g) = v;
}

// =====================================================================
// bf16 MFMA GEMM, QKV (R11 structure, byte-identical: T4 3-buffer
// counted-vmcnt pipeline, vmcnt(4)+lgkmcnt(0) steady state).
//   z=0: A=Wq, B=x (m=hd, n=token) -> Q[b,h,t,d] * QSCALE
//   z=1: A=Wk, B=x                  -> K[b,h,t,d]
//   z=2: A=x,  B=Wv (m=token, n=hd) -> Vt[b,h,d,t]
// =====================================================================
#define LSTR 136   // LDS transpose stride (16B-aligned rows, conflict-free)
#define DBUF 8192  // elems per staging buffer (As 4096 + Bs 4096)

__global__ __launch_bounds__(256)
void gemm_qkv(const __bf16* __restrict__ X,
              const __bf16* __restrict__ W0, const __bf16* __restrict__ W1,
              const __bf16* __restrict__ W2,
              __bf16* __restrict__ Oq, __bf16* __restrict__ Ok,
              __bf16* __restrict__ Ovt)
{
    const int z = blockIdx.z;
    const __bf16 *A, *B;
    int m0, n0;
    if (z < 2) {                     // W·x^T : m=hd(1024), n=token(4096)
        A = z ? W1 : W0; B = X;
        m0 = blockIdx.y * 128; n0 = blockIdx.x * 128;
    } else {                         // x·Wv^T : m=token, n=hd
        A = X; B = W2;
        m0 = blockIdx.x * 128; n0 = blockIdx.y * 128;
    }

    // union: 3-buffer staging (24576 elems) / 128x136 transpose (17408)
    __shared__ __attribute__((aligned(16))) __bf16 smem[3 * DBUF];

    const int tid  = threadIdx.x;
    const int lane = tid & 63;
    const int wave = tid >> 6;
    const int wm = wave & 1, wn = wave >> 1;
    const int col = lane & 15, quad = lane >> 4;

    const __bf16* Ag = A + (size_t)(m0 + (tid >> 2)) * DM + (tid & 3) * 8;
    const __bf16* Bg = B + (size_t)(n0 + (tid >> 2)) * DM + (tid & 3) * 8;
    const int lo = tid * 8;   // this thread's 16B slot within a buffer

#define QSTAGE(d, k) do {                                            \
        GLDS16(Ag + (k) * 32,                   (d) + lo);           \
        GLDS16(Ag + (size_t)64 * DM + (k) * 32, (d) + lo + 2048);    \
        GLDS16(Bg + (k) * 32,                   (d) + 4096 + lo);    \
        GLDS16(Bg + (size_t)64 * DM + (k) * 32, (d) + 4096 + lo + 2048); \
    } while (0)

#define QCOMP(p) do {                                                        \
        const __bf16* Asr = (p);                                             \
        const __bf16* Bsr = (p) + 4096;                                     \
        bf16x8 af[4], bfr[4];                                                \
        _Pragma("unroll")                                                    \
        for (int i = 0; i < 4; ++i)                                          \
            af[i] = *(const bf16x8*)&Asr[(wm * 64 + i * 16 + col) * 32 + quad * 8]; \
        _Pragma("unroll")                                                    \
        for (int j = 0; j < 4; ++j)                                          \
            bfr[j] = *(const bf16x8*)&Bsr[(wn * 64 + j * 16 + col) * 32 + quad * 8]; \
        _Pragma("unroll")                                                    \
        for (int i = 0; i < 4; ++i)                                          \
            _Pragma("unroll")                                                \
            for (int j = 0; j < 4; ++j)                                      \
                acc[i][j] = __builtin_amdgcn_mfma_f32_16x16x32_bf16(af[i], bfr[j], acc[i][j], 0, 0, 0); \
    } while (0)

    f32x4 acc[4][4];
#pragma unroll
    for (int i = 0; i < 4; ++i)
#pragma unroll
        for (int j = 0; j < 4; ++j)
#pragma unroll
            for (int r = 0; r < 4; ++r) acc[i][j][r] = 0.0f;

    __bf16 *b0 = smem, *b1 = smem + DBUF, *b2 = smem + 2 * DBUF;

    // ---- prologue: issue tiles 0 and 1 (8 loads outstanding) ----
    QSTAGE(b0, 0);
    QSTAGE(b1, 1);

    const int nk = DM / 32;   // 32 K-steps
    for (int t = 0; t < nk - 1; ++t) {
        WB(4);                         // tile t landed; t+1's 4 in flight
        if (t + 2 < nk) QSTAGE(b2, t + 2);
        QCOMP(b0);
        __bf16* tmp = b0; b0 = b1; b1 = b2; b2 = tmp;
    }
    WB(0);                             // final tile landed
    QCOMP(b0);

    // ---- LDS transpose -> packed global stores ----
    __syncthreads();   // full drain: staging reads done, smem reusable
    const float sc = (z == 0) ? QSCALE : 1.0f;
#pragma unroll
    for (int i = 0; i < 4; ++i)
#pragma unroll
        for (int j = 0; j < 4; ++j) {
            const int ml = wm * 64 + i * 16 + quad * 4;
            const int nl = wn * 64 + j * 16 + col;
            bf16x4 pk;
#pragma unroll
            for (int r = 0; r < 4; ++r) pk[r] = (__bf16)(acc[i][j][r] * sc);
            *(bf16x4*)&smem[nl * LSTR + ml] = pk;   // Ls[n][m]
        }
    __syncthreads();

#pragma unroll
    for (int it = 0; it < 8; ++it) {
        int c   = tid + 256 * it;
        int row = c >> 4;          // n_local
        int ch  = (c & 15) * 8;    // m_local base
        bf16x8 v = *(const bf16x8*)&smem[row * LSTR + ch];
        if (z < 2) {
            int t  = n0 + row;
            int b  = t >> 11; t &= 2047;
            int hd = m0 + ch;
            int h  = hd >> 6, d = hd & 63;
            *(bf16x8*)&((z ? Ok : Oq)[(((size_t)(b * 16 + h)) * TTOK + t) * 64 + d]) = v;
        } else {
            int hd = n0 + row;
            int h  = hd >> 6, d = hd & 63;
            int t  = m0 + ch;
            int b  = t >> 11; t &= 2047;
            *(bf16x8*)&Ovt[(((size_t)(b * 16 + h)) * 64 + d) * TTOK + t] = v;
        }
    }
#undef QSTAGE
#undef QCOMP
}

// =====================================================================
// out-proj v2: out[m][n] = sum_k Zm[m,k]*Wo[n,k], fp32 out.
// R12 change: BM=64 x BN=64 -> grid (16,64) = 1024 blocks = 4 blocks/CU
// = 4 waves/SIMD (was 2). The attn ladder (R5 2w=55.2, R7 4w=50.8,
// R8 2w=66.2) proved this latency-chain regime is TLP-hidden; oproj at
// 2 waves/SIMD with an 8-MFMA phase was ~95% stall. Per-wave step now:
// 1 A-read + 4 B-reads + 4 MFMA (shorter chain). T4 3-buffer pipeline
// kept (2 loads/thread/tile -> vmcnt(2) steady). Bijective XCD swizzle:
// XCD c owns m-rows [512c,512c+512) -> 1MB Zm + 2MB Wo = 3MB <= 4MB L2.
// LDS 3 x 4096 elems = 24 KB (no occupancy constraint; grid-limited 4/CU).
// =====================================================================
#define ODBUF 4096   // elems per staging buffer (As 2048 + Bs 2048)

__global__ __launch_bounds__(256)
void gemm_oproj(const __bf16* __restrict__ X, const __bf16* __restrict__ Wo,
                float* __restrict__ Of)
{
    const int f = blockIdx.x + 16 * blockIdx.y;  // 0..1023 dispatch-linear
    const int c = f & 7, i0 = f >> 3;            // XCD c (16%8==0 -> c=x&7)
    const int m0 = (8 * c + (i0 & 7)) * 64;      // XCD c -> m-rows [512c,512c+512)
    const int n0 = (i0 >> 3) * 64;               // 16 n-tiles of 64

    __shared__ __attribute__((aligned(16))) __bf16 smem[3 * ODBUF];

    const int tid  = threadIdx.x;
    const int lane = tid & 63;
    const int wave = tid >> 6;
    const int col = lane & 15, quad = lane >> 4;

    const __bf16* Ag = X  + (size_t)(m0 + (tid >> 2)) * DM + (tid & 3) * 8;  // 64 rows
    const __bf16* Bg = Wo + (size_t)(n0 + (tid >> 2)) * DM + (tid & 3) * 8;  // 64 rows
    const int lo = tid * 8;

#define OSTAGE(d, k) do {                                            \
        GLDS16(Ag + (k) * 32, (d) + lo);                             \
        GLDS16(Bg + (k) * 32, (d) + 2048 + lo);                      \
    } while (0)

#define OCOMP(p) do {                                                        \
        const __bf16* Asr = (p);                                             \
        const __bf16* Bsr = (p) + 2048;                                     \
        bf16x8 af = *(const bf16x8*)&Asr[(wave * 16 + col) * 32 + quad * 8]; \
        bf16x8 bfr[4];                                                       \
        _Pragma("unroll")                                                    \
        for (int j = 0; j < 4; ++j)                                          \
            bfr[j] = *(const bf16x8*)&Bsr[(j * 16 + col) * 32 + quad * 8];   \
        _Pragma("unroll")                                                    \
        for (int j = 0; j < 4; ++j)                                          \
            acc[j] = __builtin_amdgcn_mfma_f32_16x16x32_bf16(af, bfr[j], acc[j], 0, 0, 0); \
    } while (0)

    f32x4 acc[4];
#pragma unroll
    for (int j = 0; j < 4; ++j)
#pragma unroll
        for (int r = 0; r < 4; ++r) acc[j][r] = 0.0f;

    __bf16 *b0 = smem, *b1 = smem + ODBUF, *b2 = smem + 2 * ODBUF;

    OSTAGE(b0, 0);
    OSTAGE(b1, 1);

    const int nk = DM / 32;
    for (int t = 0; t < nk - 1; ++t) {
        WB(2);                         // tile t landed; t+1's 2 in flight
        if (t + 2 < nk) OSTAGE(b2, t + 2);
        OCOMP(b0);
        __bf16* tmp = b0; b0 = b1; b1 = b2; b2 = tmp;
    }
    WB(0);
    OCOMP(b0);

    // scalar n-fastest fp32 stores: 16 lanes = 64B contiguous
#pragma unroll
    for (int j = 0; j < 4; ++j) {
        const int mb = m0 + wave * 16 + quad * 4;
        const int n  = n0 + j * 16 + col;
#pragma unroll
        for (int r = 0; r < 4; ++r)
            Of[(size_t)(mb + r) * DM + n] = acc[j][r];
    }
#undef OSTAGE
#undef OCOMP
}

// =====================================================================
// MFMA flash attention v12 (byte-identical to R9/R11: best measured,
// 50.5us; 8-wave KV-split, in-register P, stride-72 K/V, 1 barrier/tile)
// =====================================================================
__global__ __launch_bounds__(512)
__attribute__((amdgpu_waves_per_eu(4)))
void attn_mfma(const __bf16* __restrict__ Qg, const __bf16* __restrict__ Kg,
               const __bf16* __restrict__ Vtg, __bf16* __restrict__ Zm)
{
    const int bh = blockIdx.y;
    const int q0 = blockIdx.x * 128;
    const size_t base = (size_t)bh * TTOK * 64;

    // [half][kv][buf][64*72]; reused as float combine buffer post-loop
    __shared__ __attribute__((aligned(16))) __bf16 lds[2][2][2][64 * 72];

    const int tid  = threadIdx.x;          // 0..511
    const int lane = tid & 63;
    const int wave = tid >> 6;             // 0..7
    const int half = wave >> 2;            // key range half
    const int qw   = wave & 3;             // q-set
    const int c32  = lane & 31, h32 = lane >> 5;

    // ---- Q frags: direct global -> regs (pre-scaled by QSCALE in GEMM) ----
    bf16x8 qf[4];
    const __bf16* qrow = Qg + base + (size_t)(q0 + qw * 32 + c32) * 64 + h32 * 8;
#pragma unroll
    for (int st = 0; st < 4; ++st)
        qf[st] = *(const bf16x8*)(qrow + st * 16);

    f32x16 O[2];
#pragma unroll
    for (int r = 0; r < 16; ++r) { O[0][r] = 0.0f; O[1][r] = 0.0f; }
    float lsum = 0.0f;

    // staging coords within this half's 256-thread group
    const int tid8 = tid & 255;
    const int rs   = tid8 >> 2;            // 0..63
    const int soff = (tid8 & 3) * 16;
    const int kb0  = half * 1024;          // key base for this half

    // ---- prologue: tile 0 -> buf0 ; tile 1 -> regs ----
    {
        const __bf16* kp = Kg  + base + (size_t)(kb0 + rs) * 64 + soff;
        const __bf16* vp = Vtg + base + (size_t)rs * TTOK + kb0 + soff;
        bf16x8 k0 = *(const bf16x8*)(kp);
        bf16x8 k1 = *(const bf16x8*)(kp + 8);
        bf16x8 v0 = *(const bf16x8*)(vp);
        bf16x8 v1 = *(const bf16x8*)(vp + 8);
        *(bf16x8*)&lds[half][0][0][rs * 72 + soff]     = k0;
        *(bf16x8*)&lds[half][0][0][rs * 72 + soff + 8] = k1;
        *(bf16x8*)&lds[half][1][0][rs * 72 + soff]     = v0;
        *(bf16x8*)&lds[half][1][0][rs * 72 + soff + 8] = v1;
    }
    bf16x8 kr0, kr1, vr0, vr1;
    {
        const __bf16* kp = Kg  + base + (size_t)(kb0 + 64 + rs) * 64 + soff;
        const __bf16* vp = Vtg + base + (size_t)rs * TTOK + kb0 + 64 + soff;
        kr0 = *(const bf16x8*)(kp); kr1 = *(const bf16x8*)(kp + 8);
        vr0 = *(const bf16x8*)(vp); vr1 = *(const bf16x8*)(vp + 8);
    }
    __syncthreads();

    for (int it = 0; it < 16; ++it) {
        const int cur = it & 1;
        const __bf16* Kc = &lds[half][0][cur][0];
        const __bf16* Vc = &lds[half][1][cur][0];

        // ---- S^T = K·Q^T ----
        f32x16 s0, s1;
#pragma unroll
        for (int r = 0; r < 16; ++r) { s0[r] = 0.0f; s1[r] = 0.0f; }
#pragma unroll
        for (int st = 0; st < 4; ++st) {
            bf16x8 a0 = *(const bf16x8*)&Kc[(c32)      * 72 + h32 * 8 + st * 16];
            bf16x8 a1 = *(const bf16x8*)&Kc[(32 + c32) * 72 + h32 * 8 + st * 16];
            s0 = __builtin_amdgcn_mfma_f32_32x32x16_bf16(a0, qf[st], s0, 0, 0, 0);
            s1 = __builtin_amdgcn_mfma_f32_32x32x16_bf16(a1, qf[st], s1, 0, 0, 0);
        }

        // ---- fused per-ks: exp2 -> pack -> half-exchange -> PV ----
#pragma unroll
        for (int ks = 0; ks < 4; ++ks) {
            const f32x16& sv = (ks & 2) ? s1 : s0;
            const int rb = (ks & 1) * 8;
            float p0 = EXP2F(sv[rb + 0]), p1 = EXP2F(sv[rb + 1]);
            float p2 = EXP2F(sv[rb + 2]), p3 = EXP2F(sv[rb + 3]);
            float p4 = EXP2F(sv[rb + 4]), p5 = EXP2F(sv[rb + 5]);
            float p6 = EXP2F(sv[rb + 6]), p7 = EXP2F(sv[rb + 7]);
            lsum += ((p0 + p1) + (p2 + p3)) + ((p4 + p5) + (p6 + p7));
            unsigned A0 = pk2(p0, p1), A1 = pk2(p2, p3);
            unsigned B0 = pk2(p4, p5), B1 = pk2(p6, p7);
            unsigned s0w = h32 ? A0 : B0;
            unsigned s1w = h32 ? A1 : B1;
            unsigned r0 = __shfl_xor(s0w, 32, 64);
            unsigned r1 = __shfl_xor(s1w, 32, 64);
            FU fu;
            fu.u[0] = h32 ? r0 : A0;
            fu.u[1] = h32 ? r1 : A1;
            fu.u[2] = h32 ? B0 : r0;
            fu.u[3] = h32 ? B1 : r1;
            bf16x8 v0 = *(const bf16x8*)&Vc[(c32)      * 72 + h32 * 8 + ks * 16];
            bf16x8 v1 = *(const bf16x8*)&Vc[(32 + c32) * 72 + h32 * 8 + ks * 16];
            O[0] = __builtin_amdgcn_mfma_f32_32x32x16_bf16(v0, fu.v, O[0], 0, 0, 0);
            O[1] = __builtin_amdgcn_mfma_f32_32x32x16_bf16(v1, fu.v, O[1], 0, 0, 0);
        }

        // ---- stage tile it+1 (in regs) -> other buffer ----
        *(bf16x8*)&lds[half][0][cur ^ 1][rs * 72 + soff]     = kr0;
        *(bf16x8*)&lds[half][0][cur ^ 1][rs * 72 + soff + 8] = kr1;
        *(bf16x8*)&lds[half][1][cur ^ 1][rs * 72 + soff]     = vr0;
        *(bf16x8*)&lds[half][1][cur ^ 1][rs * 72 + soff + 8] = vr1;

        // ---- prefetch tile it+2 ----
        {
            int itn = (it + 2) & 15;
            const __bf16* kp = Kg  + base + (size_t)(kb0 + itn * 64 + rs) * 64 + soff;
            const __bf16* vp = Vtg + base + (size_t)rs * TTOK + kb0 + itn * 64 + soff;
            kr0 = *(const bf16x8*)(kp); kr1 = *(const bf16x8*)(kp + 8);
            vr0 = *(const bf16x8*)(vp); vr1 = *(const bf16x8*)(vp + 8);
        }

        // ONE barrier per tile: next-buf writes visible; cur-buf reads done
        __syncthreads();
    }

    // ---- combine halves: waves 4-7 deposit partials, waves 0-3 merge ----
    // layout [qw][r][lane]: 64 consecutive floats per row -> conflict-free
    float* cb = (float*)&lds[0][0][0][0];   // 33 KB < 72 KB, post-barrier safe
    if (wave >= 4) {
        float* me = cb + qw * 2048;
#pragma unroll
        for (int r = 0; r < 16; ++r) {
            me[r * 64 + lane]        = O[0][r];
            me[(16 + r) * 64 + lane] = O[1][r];
        }
        cb[8192 + qw * 64 + lane] = lsum;
    }
    __syncthreads();
    if (wave >= 4) return;
    {
        const float* pr = cb + qw * 2048;
#pragma unroll
        for (int r = 0; r < 16; ++r) {
            O[0][r] += pr[r * 64 + lane];
            O[1][r] += pr[(16 + r) * 64 + lane];
        }
        lsum += cb[8192 + qw * 64 + lane];
    }
    const float ltot = lsum + __shfl_xor(lsum, 32, 64);
    const float inv  = 1.0f / ltot;

    // ---- vq: one-time coalesced global re-read of own-q V column ----
    const int q = q0 + qw * 32 + c32;
    float vq[2][16];
#pragma unroll
    for (int db = 0; db < 2; ++db)
#pragma unroll
        for (int rg = 0; rg < 16; ++rg) {
            int d = db * 32 + (rg & 3) + 8 * (rg >> 2) + 4 * h32;
            vq[db][rg] = (float)Vtg[base + (size_t)d * TTOK + q];
        }

    // ---- epilogue: Y = O/l ; exclusive output mod ; packed bf16 store ----
    const int b = bh >> 4, h = bh & 15;
    float y[2][16];
    float yv = 0.f, v2 = 0.f, yy = 0.f;
#pragma unroll
    for (int db = 0; db < 2; ++db)
#pragma unroll
        for (int rg = 0; rg < 16; ++rg) {
            float yval = O[db][rg] * inv;
            float vval = vq[db][rg];
            y[db][rg] = yval;
            yv += yval * vval; v2 += vval * vval; yy += yval * yval;
        }
    yv += __shfl_xor(yv, 32, 64);
    v2 += __shfl_xor(v2, 32, 64);
    yy += __shfl_xor(yy, 32, 64);
    float scl = (v2 > 0.0f) ? yv / fmaxf(v2, 1.1754943508222875e-38f) : 0.0f;
    float zz = 0.f;
    float zvv[2][16];
#pragma unroll
    for (int db = 0; db < 2; ++db)
#pragma unroll
        for (int rg = 0; rg < 16; ++rg) {
            zvv[db][rg] = y[db][rg] - scl * vq[db][rg];
            zz += zvv[db][rg] * zvv[db][rg];
        }
    zz += __shfl_xor(zz, 32, 64);
    float znorm = sqrtf(zz);
    float refn  = fmaxf(sqrtf(yy), sqrtf(v2));
    bool  wipe  = (v2 > 0.0f) && (znorm <= 1.1920928955078125e-07f * 64.0f * refn);
#pragma unroll
    for (int db = 0; db < 2; ++db)
#pragma unroll
        for (int g = 0; g < 4; ++g) {
            bf16x4 pk;
#pragma unroll
            for (int r = 0; r < 4; ++r)
                pk[r] = (__bf16)(wipe ? 0.0f : zvv[db][4 * g + r]);
            int d = db * 32 + 8 * g + 4 * h32;
            *(bf16x4*)&Zm[((size_t)(b * TTOK + q)) * DM + h * 64 + d] = pk;
        }
}

// =====================================================================
extern "C" void kernel_launch(void* const* d_in, const int* in_sizes, int n_in,
                              void* d_out, int out_size, void* d_ws, size_t ws_size,
                              hipStream_t stream) {
    const float* x  = (const float*)d_in[0];
    const float* Wq = (const float*)d_in[1];
    const float* Wk = (const float*)d_in[2];
    const float* Wv = (const float*)d_in[3];
    const float* Wo = (const float*)d_in[4];

    const size_t NX = (size_t)NTOK * DM;   // 4M
    const size_t NW = (size_t)DM * DM;     // 1M
    __bf16* xb  = (__bf16*)d_ws;
    __bf16* wqb = xb  + NX;
    __bf16* wkb = wqb + NW;
    __bf16* wvb = wkb + NW;
    __bf16* wob = wvb + NW;
    __bf16* Qb  = wob + NW;
    __bf16* Kb  = Qb  + NX;
    __bf16* Vtb = Kb  + NX;
    __bf16* Zmb = Vtb + NX;   // total 24M bf16 = 48 MB

    cvt_all<<<(NX + 4 * NW) / 2048, 256, 0, stream>>>(x, Wq, Wk, Wv, Wo, xb);

    // QKV: z0/z1 = Wq,Wk · x^T ; z2 = x · Wv^T  (LDS-transpose epilogues)
    gemm_qkv<<<dim3(32, 8, 3), 256, 0, stream>>>(
        xb, wqb, wkb, wvb, Qb, Kb, Vtb);

    // attn: 8-wave KV-split blocks (512 thr), 2 blocks/CU = 4 waves/SIMD
    attn_mfma<<<dim3(TTOK / 128, 32), 512, 0, stream>>>(Qb, Kb, Vtb, Zmb);

    // out = Zm · Wo^T (BM=64 x BN=64, 1024 blocks = 4/CU, XCD-swizzled)
    gemm_oproj<<<dim3(16, 64), 256, 0, stream>>>(Zmb, wob, (float*)d_out);
}

// Round 13
// 178.370 us; speedup vs baseline: 1.0287x; 1.0287x over previous
//
#include <hip/hip_runtime.h>
#include <math.h>

#define DM   1024
#define TTOK 2048
#define NTOK 4096   // B*T

typedef __bf16 bf16x8 __attribute__((ext_vector_type(8)));
typedef __bf16 bf16x4 __attribute__((ext_vector_type(4)));
typedef __bf16 bf16x2 __attribute__((ext_vector_type(2)));
typedef float  f32x4  __attribute__((ext_vector_type(4)));
typedef float  f32x16 __attribute__((ext_vector_type(16)));

// Q pre-scale: sm_scale (1/8) * log2(e)  -> allows p = exp2(s)
#define QSCALE 0.18033688011112042f

#if defined(__has_builtin)
#if __has_builtin(__builtin_amdgcn_exp2f)
#define EXP2F(x) __builtin_amdgcn_exp2f(x)
#endif
#endif
#ifndef EXP2F
#define EXP2F(x) exp2f(x)
#endif

#define GLDS16(g, l) __builtin_amdgcn_global_load_lds( \
    (__attribute__((address_space(1))) void*)(g),      \
    (__attribute__((address_space(3))) void*)(l), 16, 0, 0)

// counted-vmcnt barrier (T4): wait for all but N outstanding VMEM ops,
// drain LDS-op queue (lgkmcnt(0) — REQUIRED: R10's race was the missing
// lgkmcnt; a wave could cross the barrier with ds_reads still queued and
// another wave's global_load_lds overwrote the buffer), then barrier.
// VMEM never drains to 0 in the main loop.
#define WB(N) asm volatile("s_waitcnt vmcnt(" #N ") lgkmcnt(0)\n\ts_barrier" ::: "memory")

// pack two f32 -> one dword of 2 bf16 (RNE, same rounding as (__bf16) cast)
__device__ __forceinline__ unsigned pk2(float a, float b) {
    bf16x2 t; t[0] = (__bf16)a; t[1] = (__bf16)b;
    return __builtin_bit_cast(unsigned, t);
}
union FU { unsigned u[4]; bf16x8 v; };

// ---------------- fp32 -> bf16 convert: x + 4 weights in ONE launch ----------------
__global__ __launch_bounds__(256)
void cvt_all(const float* __restrict__ x,  const float* __restrict__ Wq,
             const float* __restrict__ Wk, const float* __restrict__ Wv,
             const float* __restrict__ Wo, __bf16* __restrict__ dst) {
    size_t g = ((size_t)blockIdx.x * 256 + threadIdx.x) * 8;
    const float* s;
    size_t off;
    const size_t NX = (size_t)NTOK * DM;   // 4M
    if (g < NX) { s = x; off = g; }
    else {
        size_t gg = g - NX;
        int w = (int)(gg >> 20);           // 1M-element segments
        off = gg & ((1u << 20) - 1);
        s = (w == 0) ? Wq : (w == 1) ? Wk : (w == 2) ? Wv : Wo;
    }
    float4 a = *(const float4*)(s + off);
    float4 b = *(const float4*)(s + off + 4);
    bf16x8 v;
    v[0] = (__bf16)a.x; v[1] = (__bf16)a.y; v[2] = (__bf16)a.z; v[3] = (__bf16)a.w;
    v[4] = (__bf16)b.x; v[5] = (__bf16)b.y; v[6] = (__bf16)b.z; v[7] = (__bf16)b.w;
    *(bf16x8*)(dst + g) = v;
}

// =====================================================================
// bf16 MFMA GEMM, QKV (R11 structure, byte-identical: T4 3-buffer
// counted-vmcnt pipeline, vmcnt(4)+lgkmcnt(0) steady state).
//   z=0: A=Wq, B=x (m=hd, n=token) -> Q[b,h,t,d] * QSCALE
//   z=1: A=Wk, B=x                  -> K[b,h,t,d]
//   z=2: A=x,  B=Wv (m=token, n=hd) -> Vt[b,h,d,t]
// =====================================================================
#define LSTR 136   // LDS transpose stride (16B-aligned rows, conflict-free)
#define DBUF 8192  // elems per staging buffer (As 4096 + Bs 4096)

__global__ __launch_bounds__(256)
void gemm_qkv(const __bf16* __restrict__ X,
              const __bf16* __restrict__ W0, const __bf16* __restrict__ W1,
              const __bf16* __restrict__ W2,
              __bf16* __restrict__ Oq, __bf16* __restrict__ Ok,
              __bf16* __restrict__ Ovt)
{
    const int z = blockIdx.z;
    const __bf16 *A, *B;
    int m0, n0;
    if (z < 2) {                     // W·x^T : m=hd(1024), n=token(4096)
        A = z ? W1 : W0; B = X;
        m0 = blockIdx.y * 128; n0 = blockIdx.x * 128;
    } else {                         // x·Wv^T : m=token, n=hd
        A = X; B = W2;
        m0 = blockIdx.x * 128; n0 = blockIdx.y * 128;
    }

    // union: 3-buffer staging (24576 elems) / 128x136 transpose (17408)
    __shared__ __attribute__((aligned(16))) __bf16 smem[3 * DBUF];

    const int tid  = threadIdx.x;
    const int lane = tid & 63;
    const int wave = tid >> 6;
    const int wm = wave & 1, wn = wave >> 1;
    const int col = lane & 15, quad = lane >> 4;

    const __bf16* Ag = A + (size_t)(m0 + (tid >> 2)) * DM + (tid & 3) * 8;
    const __bf16* Bg = B + (size_t)(n0 + (tid >> 2)) * DM + (tid & 3) * 8;
    const int lo = tid * 8;   // this thread's 16B slot within a buffer

#define QSTAGE(d, k) do {                                            \
        GLDS16(Ag + (k) * 32,                   (d) + lo);           \
        GLDS16(Ag + (size_t)64 * DM + (k) * 32, (d) + lo + 2048);    \
        GLDS16(Bg + (k) * 32,                   (d) + 4096 + lo);    \
        GLDS16(Bg + (size_t)64 * DM + (k) * 32, (d) + 4096 + lo + 2048); \
    } while (0)

#define QCOMP(p) do {                                                        \
        const __bf16* Asr = (p);                                             \
        const __bf16* Bsr = (p) + 4096;                                     \
        bf16x8 af[4], bfr[4];                                                \
        _Pragma("unroll")                                                    \
        for (int i = 0; i < 4; ++i)                                          \
            af[i] = *(const bf16x8*)&Asr[(wm * 64 + i * 16 + col) * 32 + quad * 8]; \
        _Pragma("unroll")                                                    \
        for (int j = 0; j < 4; ++j)                                          \
            bfr[j] = *(const bf16x8*)&Bsr[(wn * 64 + j * 16 + col) * 32 + quad * 8]; \
        _Pragma("unroll")                                                    \
        for (int i = 0; i < 4; ++i)                                          \
            _Pragma("unroll")                                                \
            for (int j = 0; j < 4; ++j)                                      \
                acc[i][j] = __builtin_amdgcn_mfma_f32_16x16x32_bf16(af[i], bfr[j], acc[i][j], 0, 0, 0); \
    } while (0)

    f32x4 acc[4][4];
#pragma unroll
    for (int i = 0; i < 4; ++i)
#pragma unroll
        for (int j = 0; j < 4; ++j)
#pragma unroll
            for (int r = 0; r < 4; ++r) acc[i][j][r] = 0.0f;

    __bf16 *b0 = smem, *b1 = smem + DBUF, *b2 = smem + 2 * DBUF;

    // ---- prologue: issue tiles 0 and 1 (8 loads outstanding) ----
    QSTAGE(b0, 0);
    QSTAGE(b1, 1);

    const int nk = DM / 32;   // 32 K-steps
    for (int t = 0; t < nk - 1; ++t) {
        WB(4);                         // tile t landed; t+1's 4 in flight
        if (t + 2 < nk) QSTAGE(b2, t + 2);
        QCOMP(b0);
        __bf16* tmp = b0; b0 = b1; b1 = b2; b2 = tmp;
    }
    WB(0);                             // final tile landed
    QCOMP(b0);

    // ---- LDS transpose -> packed global stores ----
    __syncthreads();   // full drain: staging reads done, smem reusable
    const float sc = (z == 0) ? QSCALE : 1.0f;
#pragma unroll
    for (int i = 0; i < 4; ++i)
#pragma unroll
        for (int j = 0; j < 4; ++j) {
            const int ml = wm * 64 + i * 16 + quad * 4;
            const int nl = wn * 64 + j * 16 + col;
            bf16x4 pk;
#pragma unroll
            for (int r = 0; r < 4; ++r) pk[r] = (__bf16)(acc[i][j][r] * sc);
            *(bf16x4*)&smem[nl * LSTR + ml] = pk;   // Ls[n][m]
        }
    __syncthreads();

#pragma unroll
    for (int it = 0; it < 8; ++it) {
        int c   = tid + 256 * it;
        int row = c >> 4;          // n_local
        int ch  = (c & 15) * 8;    // m_local base
        bf16x8 v = *(const bf16x8*)&smem[row * LSTR + ch];
        if (z < 2) {
            int t  = n0 + row;
            int b  = t >> 11; t &= 2047;
            int hd = m0 + ch;
            int h  = hd >> 6, d = hd & 63;
            *(bf16x8*)&((z ? Ok : Oq)[(((size_t)(b * 16 + h)) * TTOK + t) * 64 + d]) = v;
        } else {
            int hd = n0 + row;
            int h  = hd >> 6, d = hd & 63;
            int t  = m0 + ch;
            int b  = t >> 11; t &= 2047;
            *(bf16x8*)&Ovt[(((size_t)(b * 16 + h)) * 64 + d) * TTOK + t] = v;
        }
    }
#undef QSTAGE
#undef QCOMP
}

// =====================================================================
// out-proj (R11-exact, the measured-best config): out[m][n] =
// sum_k Zm[m,k]*Wo[n,k], fp32 out. BM=64 x BN=128, grid (8,64) = 512
// blocks = 2 blocks/CU. R12's BN=64 @ 4/CU regressed (+2.5us): oproj is
// TLP-insensitive and BN=64 halves B-panel reuse — reverted.
// T4 3-buffer counted-vmcnt pipeline, vmcnt(3)+lgkmcnt(0) steady state.
// Bijective XCD swizzle: XCD c owns m-rows [512c,512c+512) -> 1MB Zm +
// 2MB Wo = 3MB <= 4MB L2. LDS 3 x 6144 elems = 36.9 KB.
// =====================================================================
#define ODBUF 6144   // elems per staging buffer (As 2048 + Bs 4096)

__global__ __launch_bounds__(256)
void gemm_oproj(const __bf16* __restrict__ X, const __bf16* __restrict__ Wo,
                float* __restrict__ Of)
{
    const int f = blockIdx.x + 8 * blockIdx.y;   // 0..511 dispatch-linear
    const int c = f & 7, i0 = f >> 3;            // XCD c (round-robin)
    const int m0 = (8 * c + (i0 & 7)) * 64;      // XCD c -> m-rows [512c,512c+512)
    const int n0 = (i0 >> 3) * 128;

    __shared__ __attribute__((aligned(16))) __bf16 smem[3 * ODBUF];

    const int tid  = threadIdx.x;
    const int lane = tid & 63;
    const int wave = tid >> 6;
    const int col = lane & 15, quad = lane >> 4;

    const __bf16* Ag = X  + (size_t)(m0 + (tid >> 2)) * DM + (tid & 3) * 8;  // 64 rows
    const __bf16* Bg = Wo + (size_t)(n0 + (tid >> 2)) * DM + (tid & 3) * 8;  // 128 rows
    const int lo = tid * 8;

#define OSTAGE(d, k) do {                                            \
        GLDS16(Ag + (k) * 32,                   (d) + lo);           \
        GLDS16(Bg + (k) * 32,                   (d) + 2048 + lo);    \
        GLDS16(Bg + (size_t)64 * DM + (k) * 32, (d) + 2048 + lo + 2048); \
    } while (0)

#define OCOMP(p) do {                                                        \
        const __bf16* Asr = (p);                                             \
        const __bf16* Bsr = (p) + 2048;                                     \
        bf16x8 af[4], bfr[2];                                                \
        _Pragma("unroll")                                                    \
        for (int i = 0; i < 4; ++i)                                          \
            af[i] = *(const bf16x8*)&Asr[(i * 16 + col) * 32 + quad * 8];    \
        _Pragma("unroll")                                                    \
        for (int j = 0; j < 2; ++j)                                          \
            bfr[j] = *(const bf16x8*)&Bsr[(wave * 32 + j * 16 + col) * 32 + quad * 8]; \
        _Pragma("unroll")                                                    \
        for (int i = 0; i < 4; ++i)                                          \
            _Pragma("unroll")                                                \
            for (int j = 0; j < 2; ++j)                                      \
                acc[i][j] = __builtin_amdgcn_mfma_f32_16x16x32_bf16(af[i], bfr[j], acc[i][j], 0, 0, 0); \
    } while (0)

    f32x4 acc[4][2];
#pragma unroll
    for (int i = 0; i < 4; ++i)
#pragma unroll
        for (int j = 0; j < 2; ++j)
#pragma unroll
            for (int r = 0; r < 4; ++r) acc[i][j][r] = 0.0f;

    __bf16 *b0 = smem, *b1 = smem + ODBUF, *b2 = smem + 2 * ODBUF;

    OSTAGE(b0, 0);
    OSTAGE(b1, 1);

    const int nk = DM / 32;
    for (int t = 0; t < nk - 1; ++t) {
        WB(3);                         // tile t landed; t+1's 3 in flight
        if (t + 2 < nk) OSTAGE(b2, t + 2);
        OCOMP(b0);
        __bf16* tmp = b0; b0 = b1; b1 = b2; b2 = tmp;
    }
    WB(0);
    OCOMP(b0);

    // scalar n-fastest fp32 stores: 16 lanes = 64B contiguous
#pragma unroll
    for (int i = 0; i < 4; ++i)
#pragma unroll
        for (int j = 0; j < 2; ++j) {
            const int mb = m0 + i * 16 + quad * 4;
            const int n  = n0 + wave * 32 + j * 16 + col;
#pragma unroll
            for (int r = 0; r < 4; ++r)
                Of[(size_t)(mb + r) * DM + n] = acc[i][j][r];
        }
#undef OSTAGE
#undef OCOMP
}

// =====================================================================
// MFMA flash attention v12 (byte-identical to R9/R11: best measured,
// 50.5us; 8-wave KV-split, in-register P, stride-72 K/V, 1 barrier/tile)
// =====================================================================
__global__ __launch_bounds__(512)
__attribute__((amdgpu_waves_per_eu(4)))
void attn_mfma(const __bf16* __restrict__ Qg, const __bf16* __restrict__ Kg,
               const __bf16* __restrict__ Vtg, __bf16* __restrict__ Zm)
{
    const int bh = blockIdx.y;
    const int q0 = blockIdx.x * 128;
    const size_t base = (size_t)bh * TTOK * 64;

    // [half][kv][buf][64*72]; reused as float combine buffer post-loop
    __shared__ __attribute__((aligned(16))) __bf16 lds[2][2][2][64 * 72];

    const int tid  = threadIdx.x;          // 0..511
    const int lane = tid & 63;
    const int wave = tid >> 6;             // 0..7
    const int half = wave >> 2;            // key range half
    const int qw   = wave & 3;             // q-set
    const int c32  = lane & 31, h32 = lane >> 5;

    // ---- Q frags: direct global -> regs (pre-scaled by QSCALE in GEMM) ----
    bf16x8 qf[4];
    const __bf16* qrow = Qg + base + (size_t)(q0 + qw * 32 + c32) * 64 + h32 * 8;
#pragma unroll
    for (int st = 0; st < 4; ++st)
        qf[st] = *(const bf16x8*)(qrow + st * 16);

    f32x16 O[2];
#pragma unroll
    for (int r = 0; r < 16; ++r) { O[0][r] = 0.0f; O[1][r] = 0.0f; }
    float lsum = 0.0f;

    // staging coords within this half's 256-thread group
    const int tid8 = tid & 255;
    const int rs   = tid8 >> 2;            // 0..63
    const int soff = (tid8 & 3) * 16;
    const int kb0  = half * 1024;          // key base for this half

    // ---- prologue: tile 0 -> buf0 ; tile 1 -> regs ----
    {
        const __bf16* kp = Kg  + base + (size_t)(kb0 + rs) * 64 + soff;
        const __bf16* vp = Vtg + base + (size_t)rs * TTOK + kb0 + soff;
        bf16x8 k0 = *(const bf16x8*)(kp);
        bf16x8 k1 = *(const bf16x8*)(kp + 8);
        bf16x8 v0 = *(const bf16x8*)(vp);
        bf16x8 v1 = *(const bf16x8*)(vp + 8);
        *(bf16x8*)&lds[half][0][0][rs * 72 + soff]     = k0;
        *(bf16x8*)&lds[half][0][0][rs * 72 + soff + 8] = k1;
        *(bf16x8*)&lds[half][1][0][rs * 72 + soff]     = v0;
        *(bf16x8*)&lds[half][1][0][rs * 72 + soff + 8] = v1;
    }
    bf16x8 kr0, kr1, vr0, vr1;
    {
        const __bf16* kp = Kg  + base + (size_t)(kb0 + 64 + rs) * 64 + soff;
        const __bf16* vp = Vtg + base + (size_t)rs * TTOK + kb0 + 64 + soff;
        kr0 = *(const bf16x8*)(kp); kr1 = *(const bf16x8*)(kp + 8);
        vr0 = *(const bf16x8*)(vp); vr1 = *(const bf16x8*)(vp + 8);
    }
    __syncthreads();

    for (int it = 0; it < 16; ++it) {
        const int cur = it & 1;
        const __bf16* Kc = &lds[half][0][cur][0];
        const __bf16* Vc = &lds[half][1][cur][0];

        // ---- S^T = K·Q^T ----
        f32x16 s0, s1;
#pragma unroll
        for (int r = 0; r < 16; ++r) { s0[r] = 0.0f; s1[r] = 0.0f; }
#pragma unroll
        for (int st = 0; st < 4; ++st) {
            bf16x8 a0 = *(const bf16x8*)&Kc[(c32)      * 72 + h32 * 8 + st * 16];
            bf16x8 a1 = *(const bf16x8*)&Kc[(32 + c32) * 72 + h32 * 8 + st * 16];
            s0 = __builtin_amdgcn_mfma_f32_32x32x16_bf16(a0, qf[st], s0, 0, 0, 0);
            s1 = __builtin_amdgcn_mfma_f32_32x32x16_bf16(a1, qf[st], s1, 0, 0, 0);
        }

        // ---- fused per-ks: exp2 -> pack -> half-exchange -> PV ----
#pragma unroll
        for (int ks = 0; ks < 4; ++ks) {
            const f32x16& sv = (ks & 2) ? s1 : s0;
            const int rb = (ks & 1) * 8;
            float p0 = EXP2F(sv[rb + 0]), p1 = EXP2F(sv[rb + 1]);
            float p2 = EXP2F(sv[rb + 2]), p3 = EXP2F(sv[rb + 3]);
            float p4 = EXP2F(sv[rb + 4]), p5 = EXP2F(sv[rb + 5]);
            float p6 = EXP2F(sv[rb + 6]), p7 = EXP2F(sv[rb + 7]);
            lsum += ((p0 + p1) + (p2 + p3)) + ((p4 + p5) + (p6 + p7));
            unsigned A0 = pk2(p0, p1), A1 = pk2(p2, p3);
            unsigned B0 = pk2(p4, p5), B1 = pk2(p6, p7);
            unsigned s0w = h32 ? A0 : B0;
            unsigned s1w = h32 ? A1 : B1;
            unsigned r0 = __shfl_xor(s0w, 32, 64);
            unsigned r1 = __shfl_xor(s1w, 32, 64);
            FU fu;
            fu.u[0] = h32 ? r0 : A0;
            fu.u[1] = h32 ? r1 : A1;
            fu.u[2] = h32 ? B0 : r0;
            fu.u[3] = h32 ? B1 : r1;
            bf16x8 v0 = *(const bf16x8*)&Vc[(c32)      * 72 + h32 * 8 + ks * 16];
            bf16x8 v1 = *(const bf16x8*)&Vc[(32 + c32) * 72 + h32 * 8 + ks * 16];
            O[0] = __builtin_amdgcn_mfma_f32_32x32x16_bf16(v0, fu.v, O[0], 0, 0, 0);
            O[1] = __builtin_amdgcn_mfma_f32_32x32x16_bf16(v1, fu.v, O[1], 0, 0, 0);
        }

        // ---- stage tile it+1 (in regs) -> other buffer ----
        *(bf16x8*)&lds[half][0][cur ^ 1][rs * 72 + soff]     = kr0;
        *(bf16x8*)&lds[half][0][cur ^ 1][rs * 72 + soff + 8] = kr1;
        *(bf16x8*)&lds[half][1][cur ^ 1][rs * 72 + soff]     = vr0;
        *(bf16x8*)&lds[half][1][cur ^ 1][rs * 72 + soff + 8] = vr1;

        // ---- prefetch tile it+2 ----
        {
            int itn = (it + 2) & 15;
            const __bf16* kp = Kg  + base + (size_t)(kb0 + itn * 64 + rs) * 64 + soff;
            const __bf16* vp = Vtg + base + (size_t)rs * TTOK + kb0 + itn * 64 + soff;
            kr0 = *(const bf16x8*)(kp); kr1 = *(const bf16x8*)(kp + 8);
            vr0 = *(const bf16x8*)(vp); vr1 = *(const bf16x8*)(vp + 8);
        }

        // ONE barrier per tile: next-buf writes visible; cur-buf reads done
        __syncthreads();
    }

    // ---- combine halves: waves 4-7 deposit partials, waves 0-3 merge ----
    // layout [qw][r][lane]: 64 consecutive floats per row -> conflict-free
    float* cb = (float*)&lds[0][0][0][0];   // 33 KB < 72 KB, post-barrier safe
    if (wave >= 4) {
        float* me = cb + qw * 2048;
#pragma unroll
        for (int r = 0; r < 16; ++r) {
            me[r * 64 + lane]        = O[0][r];
            me[(16 + r) * 64 + lane] = O[1][r];
        }
        cb[8192 + qw * 64 + lane] = lsum;
    }
    __syncthreads();
    if (wave >= 4) return;
    {
        const float* pr = cb + qw * 2048;
#pragma unroll
        for (int r = 0; r < 16; ++r) {
            O[0][r] += pr[r * 64 + lane];
            O[1][r] += pr[(16 + r) * 64 + lane];
        }
        lsum += cb[8192 + qw * 64 + lane];
    }
    const float ltot = lsum + __shfl_xor(lsum, 32, 64);
    const float inv  = 1.0f / ltot;

    // ---- vq: one-time coalesced global re-read of own-q V column ----
    const int q = q0 + qw * 32 + c32;
    float vq[2][16];
#pragma unroll
    for (int db = 0; db < 2; ++db)
#pragma unroll
        for (int rg = 0; rg < 16; ++rg) {
            int d = db * 32 + (rg & 3) + 8 * (rg >> 2) + 4 * h32;
            vq[db][rg] = (float)Vtg[base + (size_t)d * TTOK + q];
        }

    // ---- epilogue: Y = O/l ; exclusive output mod ; packed bf16 store ----
    const int b = bh >> 4, h = bh & 15;
    float y[2][16];
    float yv = 0.f, v2 = 0.f, yy = 0.f;
#pragma unroll
    for (int db = 0; db < 2; ++db)
#pragma unroll
        for (int rg = 0; rg < 16; ++rg) {
            float yval = O[db][rg] * inv;
            float vval = vq[db][rg];
            y[db][rg] = yval;
            yv += yval * vval; v2 += vval * vval; yy += yval * yval;
        }
    yv += __shfl_xor(yv, 32, 64);
    v2 += __shfl_xor(v2, 32, 64);
    yy += __shfl_xor(yy, 32, 64);
    float scl = (v2 > 0.0f) ? yv / fmaxf(v2, 1.1754943508222875e-38f) : 0.0f;
    float zz = 0.f;
    float zvv[2][16];
#pragma unroll
    for (int db = 0; db < 2; ++db)
#pragma unroll
        for (int rg = 0; rg < 16; ++rg) {
            zvv[db][rg] = y[db][rg] - scl * vq[db][rg];
            zz += zvv[db][rg] * zvv[db][rg];
        }
    zz += __shfl_xor(zz, 32, 64);
    float znorm = sqrtf(zz);
    float refn  = fmaxf(sqrtf(yy), sqrtf(v2));
    bool  wipe  = (v2 > 0.0f) && (znorm <= 1.1920928955078125e-07f * 64.0f * refn);
#pragma unroll
    for (int db = 0; db < 2; ++db)
#pragma unroll
        for (int g = 0; g < 4; ++g) {
            bf16x4 pk;
#pragma unroll
            for (int r = 0; r < 4; ++r)
                pk[r] = (__bf16)(wipe ? 0.0f : zvv[db][4 * g + r]);
            int d = db * 32 + 8 * g + 4 * h32;
            *(bf16x4*)&Zm[((size_t)(b * TTOK + q)) * DM + h * 64 + d] = pk;
        }
}

// =====================================================================
extern "C" void kernel_launch(void* const* d_in, const int* in_sizes, int n_in,
                              void* d_out, int out_size, void* d_ws, size_t ws_size,
                              hipStream_t stream) {
    const float* x  = (const float*)d_in[0];
    const float* Wq = (const float*)d_in[1];
    const float* Wk = (const float*)d_in[2];
    const float* Wv = (const float*)d_in[3];
    const float* Wo = (const float*)d_in[4];

    const size_t NX = (size_t)NTOK * DM;   // 4M
    const size_t NW = (size_t)DM * DM;     // 1M
    __bf16* xb  = (__bf16*)d_ws;
    __bf16* wqb = xb  + NX;
    __bf16* wkb = wqb + NW;
    __bf16* wvb = wkb + NW;
    __bf16* wob = wvb + NW;
    __bf16* Qb  = wob + NW;
    __bf16* Kb  = Qb  + NX;
    __bf16* Vtb = Kb  + NX;
    __bf16* Zmb = Vtb + NX;   // total 24M bf16 = 48 MB

    cvt_all<<<(NX + 4 * NW) / 2048, 256, 0, stream>>>(x, Wq, Wk, Wv, Wo, xb);

    // QKV: z0/z1 = Wq,Wk · x^T ; z2 = x · Wv^T  (LDS-transpose epilogues)
    gemm_qkv<<<dim3(32, 8, 3), 256, 0, stream>>>(
        xb, wqb, wkb, wvb, Qb, Kb, Vtb);

    // attn: 8-wave KV-split blocks (512 thr), 2 blocks/CU = 4 waves/SIMD
    attn_mfma<<<dim3(TTOK / 128, 32), 512, 0, stream>>>(Qb, Kb, Vtb, Zmb);

    // out = Zm · Wo^T (BM=64 x BN=128, 512 blocks = 2/CU, XCD-swizzled)
    gemm_oproj<<<dim3(8, 64), 256, 0, stream>>>(Zmb, wob, (float*)d_out);
}

// Round 14
// 175.727 us; speedup vs baseline: 1.0442x; 1.0150x over previous
//
#include <hip/hip_runtime.h>
#include <math.h>

#define DM   1024
#define TTOK 2048
#define NTOK 4096   // B*T

typedef __bf16 bf16x8 __attribute__((ext_vector_type(8)));
typedef __bf16 bf16x4 __attribute__((ext_vector_type(4)));
typedef __bf16 bf16x2 __attribute__((ext_vector_type(2)));
typedef float  f32x4  __attribute__((ext_vector_type(4)));
typedef float  f32x16 __attribute__((ext_vector_type(16)));

// Q pre-scale: sm_scale (1/8) * log2(e)  -> allows p = exp2(s)
#define QSCALE 0.18033688011112042f

#if defined(__has_builtin)
#if __has_builtin(__builtin_amdgcn_exp2f)
#define EXP2F(x) __builtin_amdgcn_exp2f(x)
#endif
#endif
#ifndef EXP2F
#define EXP2F(x) exp2f(x)
#endif

#define GLDS16(g, l) __builtin_amdgcn_global_load_lds( \
    (__attribute__((address_space(1))) void*)(g),      \
    (__attribute__((address_space(3))) void*)(l), 16, 0, 0)

// counted-vmcnt barrier (T4): wait for all but N outstanding VMEM ops,
// drain LDS-op queue (lgkmcnt(0) — REQUIRED: R10's race was the missing
// lgkmcnt; a wave could cross the barrier with ds_reads still queued and
// another wave's global_load_lds overwrote the buffer), then barrier.
// VMEM never drains to 0 in the main loop.
#define WB(N) asm volatile("s_waitcnt vmcnt(" #N ") lgkmcnt(0)\n\ts_barrier" ::: "memory")

// pack two f32 -> one dword of 2 bf16 (RNE, same rounding as (__bf16) cast)
__device__ __forceinline__ unsigned pk2(float a, float b) {
    bf16x2 t; t[0] = (__bf16)a; t[1] = (__bf16)b;
    return __builtin_bit_cast(unsigned, t);
}
union FU { unsigned u[4]; bf16x8 v; };

// ---------------- fp32 -> bf16 convert: x + 4 weights in ONE launch ----------------
__global__ __launch_bounds__(256)
void cvt_all(const float* __restrict__ x,  const float* __restrict__ Wq,
             const float* __restrict__ Wk, const float* __restrict__ Wv,
             const float* __restrict__ Wo, __bf16* __restrict__ dst) {
    size_t g = ((size_t)blockIdx.x * 256 + threadIdx.x) * 8;
    const float* s;
    size_t off;
    const size_t NX = (size_t)NTOK * DM;   // 4M
    if (g < NX) { s = x; off = g; }
    else {
        size_t gg = g - NX;
        int w = (int)(gg >> 20);           // 1M-element segments
        off = gg & ((1u << 20) - 1);
        s = (w == 0) ? Wq : (w == 1) ? Wk : (w == 2) ? Wv : Wo;
    }
    float4 a = *(const float4*)(s + off);
    float4 b = *(const float4*)(s + off + 4);
    bf16x8 v;
    v[0] = (__bf16)a.x; v[1] = (__bf16)a.y; v[2] = (__bf16)a.z; v[3] = (__bf16)a.w;
    v[4] = (__bf16)b.x; v[5] = (__bf16)b.y; v[6] = (__bf16)b.z; v[7] = (__bf16)b.w;
    *(bf16x8*)(dst + g) = v;
}

// =====================================================================
// bf16 MFMA GEMM, QKV (R11 structure, byte-identical: T4 3-buffer
// counted-vmcnt pipeline, vmcnt(4)+lgkmcnt(0) steady state).
//   z=0: A=Wq, B=x (m=hd, n=token) -> Q[b,h,t,d] * QSCALE
//   z=1: A=Wk, B=x                  -> K[b,h,t,d]
//   z=2: A=x,  B=Wv (m=token, n=hd) -> Vt[b,h,d,t]
// =====================================================================
#define LSTR 136   // LDS transpose stride (16B-aligned rows, conflict-free)
#define DBUF 8192  // elems per staging buffer (As 4096 + Bs 4096)

__global__ __launch_bounds__(256)
void gemm_qkv(const __bf16* __restrict__ X,
              const __bf16* __restrict__ W0, const __bf16* __restrict__ W1,
              const __bf16* __restrict__ W2,
              __bf16* __restrict__ Oq, __bf16* __restrict__ Ok,
              __bf16* __restrict__ Ovt)
{
    const int z = blockIdx.z;
    const __bf16 *A, *B;
    int m0, n0;
    if (z < 2) {                     // W·x^T : m=hd(1024), n=token(4096)
        A = z ? W1 : W0; B = X;
        m0 = blockIdx.y * 128; n0 = blockIdx.x * 128;
    } else {                         // x·Wv^T : m=token, n=hd
        A = X; B = W2;
        m0 = blockIdx.x * 128; n0 = blockIdx.y * 128;
    }

    // union: 3-buffer staging (24576 elems) / 128x136 transpose (17408)
    __shared__ __attribute__((aligned(16))) __bf16 smem[3 * DBUF];

    const int tid  = threadIdx.x;
    const int lane = tid & 63;
    const int wave = tid >> 6;
    const int wm = wave & 1, wn = wave >> 1;
    const int col = lane & 15, quad = lane >> 4;

    const __bf16* Ag = A + (size_t)(m0 + (tid >> 2)) * DM + (tid & 3) * 8;
    const __bf16* Bg = B + (size_t)(n0 + (tid >> 2)) * DM + (tid & 3) * 8;
    const int lo = tid * 8;   // this thread's 16B slot within a buffer

#define QSTAGE(d, k) do {                                            \
        GLDS16(Ag + (k) * 32,                   (d) + lo);           \
        GLDS16(Ag + (size_t)64 * DM + (k) * 32, (d) + lo + 2048);    \
        GLDS16(Bg + (k) * 32,                   (d) + 4096 + lo);    \
        GLDS16(Bg + (size_t)64 * DM + (k) * 32, (d) + 4096 + lo + 2048); \
    } while (0)

#define QCOMP(p) do {                                                        \
        const __bf16* Asr = (p);                                             \
        const __bf16* Bsr = (p) + 4096;                                     \
        bf16x8 af[4], bfr[4];                                                \
        _Pragma("unroll")                                                    \
        for (int i = 0; i < 4; ++i)                                          \
            af[i] = *(const bf16x8*)&Asr[(wm * 64 + i * 16 + col) * 32 + quad * 8]; \
        _Pragma("unroll")                                                    \
        for (int j = 0; j < 4; ++j)                                          \
            bfr[j] = *(const bf16x8*)&Bsr[(wn * 64 + j * 16 + col) * 32 + quad * 8]; \
        _Pragma("unroll")                                                    \
        for (int i = 0; i < 4; ++i)                                          \
            _Pragma("unroll")                                                \
            for (int j = 0; j < 4; ++j)                                      \
                acc[i][j] = __builtin_amdgcn_mfma_f32_16x16x32_bf16(af[i], bfr[j], acc[i][j], 0, 0, 0); \
    } while (0)

    f32x4 acc[4][4];
#pragma unroll
    for (int i = 0; i < 4; ++i)
#pragma unroll
        for (int j = 0; j < 4; ++j)
#pragma unroll
            for (int r = 0; r < 4; ++r) acc[i][j][r] = 0.0f;

    __bf16 *b0 = smem, *b1 = smem + DBUF, *b2 = smem + 2 * DBUF;

    // ---- prologue: issue tiles 0 and 1 (8 loads outstanding) ----
    QSTAGE(b0, 0);
    QSTAGE(b1, 1);

    const int nk = DM / 32;   // 32 K-steps
    for (int t = 0; t < nk - 1; ++t) {
        WB(4);                         // tile t landed; t+1's 4 in flight
        if (t + 2 < nk) QSTAGE(b2, t + 2);
        QCOMP(b0);
        __bf16* tmp = b0; b0 = b1; b1 = b2; b2 = tmp;
    }
    WB(0);                             // final tile landed
    QCOMP(b0);

    // ---- LDS transpose -> packed global stores ----
    __syncthreads();   // full drain: staging reads done, smem reusable
    const float sc = (z == 0) ? QSCALE : 1.0f;
#pragma unroll
    for (int i = 0; i < 4; ++i)
#pragma unroll
        for (int j = 0; j < 4; ++j) {
            const int ml = wm * 64 + i * 16 + quad * 4;
            const int nl = wn * 64 + j * 16 + col;
            bf16x4 pk;
#pragma unroll
            for (int r = 0; r < 4; ++r) pk[r] = (__bf16)(acc[i][j][r] * sc);
            *(bf16x4*)&smem[nl * LSTR + ml] = pk;   // Ls[n][m]
        }
    __syncthreads();

#pragma unroll
    for (int it = 0; it < 8; ++it) {
        int c   = tid + 256 * it;
        int row = c >> 4;          // n_local
        int ch  = (c & 15) * 8;    // m_local base
        bf16x8 v = *(const bf16x8*)&smem[row * LSTR + ch];
        if (z < 2) {
            int t  = n0 + row;
            int b  = t >> 11; t &= 2047;
            int hd = m0 + ch;
            int h  = hd >> 6, d = hd & 63;
            *(bf16x8*)&((z ? Ok : Oq)[(((size_t)(b * 16 + h)) * TTOK + t) * 64 + d]) = v;
        } else {
            int hd = n0 + row;
            int h  = hd >> 6, d = hd & 63;
            int t  = m0 + ch;
            int b  = t >> 11; t &= 2047;
            *(bf16x8*)&Ovt[(((size_t)(b * 16 + h)) * 64 + d) * TTOK + t] = v;
        }
    }
#undef QSTAGE
#undef QCOMP
}

// =====================================================================
// out-proj (R11-exact, measured-best): BM=64 x BN=128, grid (8,64) =
// 512 blocks = 2 blocks/CU. T4 3-buffer counted-vmcnt pipeline,
// vmcnt(3)+lgkmcnt(0) steady state. Bijective XCD swizzle: XCD c owns
// m-rows [512c,512c+512) -> 3MB <= 4MB L2. LDS 36.9 KB.
// =====================================================================
#define ODBUF 6144   // elems per staging buffer (As 2048 + Bs 4096)

__global__ __launch_bounds__(256)
void gemm_oproj(const __bf16* __restrict__ X, const __bf16* __restrict__ Wo,
                float* __restrict__ Of)
{
    const int f = blockIdx.x + 8 * blockIdx.y;   // 0..511 dispatch-linear
    const int c = f & 7, i0 = f >> 3;            // XCD c (round-robin)
    const int m0 = (8 * c + (i0 & 7)) * 64;      // XCD c -> m-rows [512c,512c+512)
    const int n0 = (i0 >> 3) * 128;

    __shared__ __attribute__((aligned(16))) __bf16 smem[3 * ODBUF];

    const int tid  = threadIdx.x;
    const int lane = tid & 63;
    const int wave = tid >> 6;
    const int col = lane & 15, quad = lane >> 4;

    const __bf16* Ag = X  + (size_t)(m0 + (tid >> 2)) * DM + (tid & 3) * 8;  // 64 rows
    const __bf16* Bg = Wo + (size_t)(n0 + (tid >> 2)) * DM + (tid & 3) * 8;  // 128 rows
    const int lo = tid * 8;

#define OSTAGE(d, k) do {                                            \
        GLDS16(Ag + (k) * 32,                   (d) + lo);           \
        GLDS16(Bg + (k) * 32,                   (d) + 2048 + lo);    \
        GLDS16(Bg + (size_t)64 * DM + (k) * 32, (d) + 2048 + lo + 2048); \
    } while (0)

#define OCOMP(p) do {                                                        \
        const __bf16* Asr = (p);                                             \
        const __bf16* Bsr = (p) + 2048;                                     \
        bf16x8 af[4], bfr[2];                                                \
        _Pragma("unroll")                                                    \
        for (int i = 0; i < 4; ++i)                                          \
            af[i] = *(const bf16x8*)&Asr[(i * 16 + col) * 32 + quad * 8];    \
        _Pragma("unroll")                                                    \
        for (int j = 0; j < 2; ++j)                                          \
            bfr[j] = *(const bf16x8*)&Bsr[(wave * 32 + j * 16 + col) * 32 + quad * 8]; \
        _Pragma("unroll")                                                    \
        for (int i = 0; i < 4; ++i)                                          \
            _Pragma("unroll")                                                \
            for (int j = 0; j < 2; ++j)                                      \
                acc[i][j] = __builtin_amdgcn_mfma_f32_16x16x32_bf16(af[i], bfr[j], acc[i][j], 0, 0, 0); \
    } while (0)

    f32x4 acc[4][2];
#pragma unroll
    for (int i = 0; i < 4; ++i)
#pragma unroll
        for (int j = 0; j < 2; ++j)
#pragma unroll
            for (int r = 0; r < 4; ++r) acc[i][j][r] = 0.0f;

    __bf16 *b0 = smem, *b1 = smem + ODBUF, *b2 = smem + 2 * ODBUF;

    OSTAGE(b0, 0);
    OSTAGE(b1, 1);

    const int nk = DM / 32;
    for (int t = 0; t < nk - 1; ++t) {
        WB(3);                         // tile t landed; t+1's 3 in flight
        if (t + 2 < nk) OSTAGE(b2, t + 2);
        OCOMP(b0);
        __bf16* tmp = b0; b0 = b1; b1 = b2; b2 = tmp;
    }
    WB(0);
    OCOMP(b0);

    // scalar n-fastest fp32 stores: 16 lanes = 64B contiguous
#pragma unroll
    for (int i = 0; i < 4; ++i)
#pragma unroll
        for (int j = 0; j < 2; ++j) {
            const int mb = m0 + i * 16 + quad * 4;
            const int n  = n0 + wave * 32 + j * 16 + col;
#pragma unroll
            for (int r = 0; r < 4; ++r)
                Of[(size_t)(mb + r) * DM + n] = acc[i][j][r];
        }
#undef OSTAGE
#undef OCOMP
}

// =====================================================================
// MFMA flash attention v13 = R13's v12 with ONE change: the per-tile
// __syncthreads() -> WB(4). The 4 prefetch loads for tile it+2 are
// issued right before the barrier; __syncthreads' vmcnt(0) drained them
// every tile (200-400cy exposed L2/L3 latency). WB(4) leaves exactly
// those 4 in flight; lgkmcnt(0) still seals buf[cur] ds_reads and the
// stage ds_writes (R10 lesson); the compiler's vmcnt-before-use covers
// kr/vr consumption at next tile's stage phase. Prologue and combine
// barriers stay full __syncthreads (cb aliases K/V LDS).
// =====================================================================
__global__ __launch_bounds__(512)
__attribute__((amdgpu_waves_per_eu(4)))
void attn_mfma(const __bf16* __restrict__ Qg, const __bf16* __restrict__ Kg,
               const __bf16* __restrict__ Vtg, __bf16* __restrict__ Zm)
{
    const int bh = blockIdx.y;
    const int q0 = blockIdx.x * 128;
    const size_t base = (size_t)bh * TTOK * 64;

    // [half][kv][buf][64*72]; reused as float combine buffer post-loop
    __shared__ __attribute__((aligned(16))) __bf16 lds[2][2][2][64 * 72];

    const int tid  = threadIdx.x;          // 0..511
    const int lane = tid & 63;
    const int wave = tid >> 6;             // 0..7
    const int half = wave >> 2;            // key range half
    const int qw   = wave & 3;             // q-set
    const int c32  = lane & 31, h32 = lane >> 5;

    // ---- Q frags: direct global -> regs (pre-scaled by QSCALE in GEMM) ----
    bf16x8 qf[4];
    const __bf16* qrow = Qg + base + (size_t)(q0 + qw * 32 + c32) * 64 + h32 * 8;
#pragma unroll
    for (int st = 0; st < 4; ++st)
        qf[st] = *(const bf16x8*)(qrow + st * 16);

    f32x16 O[2];
#pragma unroll
    for (int r = 0; r < 16; ++r) { O[0][r] = 0.0f; O[1][r] = 0.0f; }
    float lsum = 0.0f;

    // staging coords within this half's 256-thread group
    const int tid8 = tid & 255;
    const int rs   = tid8 >> 2;            // 0..63
    const int soff = (tid8 & 3) * 16;
    const int kb0  = half * 1024;          // key base for this half

    // ---- prologue: tile 0 -> buf0 ; tile 1 -> regs ----
    {
        const __bf16* kp = Kg  + base + (size_t)(kb0 + rs) * 64 + soff;
        const __bf16* vp = Vtg + base + (size_t)rs * TTOK + kb0 + soff;
        bf16x8 k0 = *(const bf16x8*)(kp);
        bf16x8 k1 = *(const bf16x8*)(kp + 8);
        bf16x8 v0 = *(const bf16x8*)(vp);
        bf16x8 v1 = *(const bf16x8*)(vp + 8);
        *(bf16x8*)&lds[half][0][0][rs * 72 + soff]     = k0;
        *(bf16x8*)&lds[half][0][0][rs * 72 + soff + 8] = k1;
        *(bf16x8*)&lds[half][1][0][rs * 72 + soff]     = v0;
        *(bf16x8*)&lds[half][1][0][rs * 72 + soff + 8] = v1;
    }
    bf16x8 kr0, kr1, vr0, vr1;
    {
        const __bf16* kp = Kg  + base + (size_t)(kb0 + 64 + rs) * 64 + soff;
        const __bf16* vp = Vtg + base + (size_t)rs * TTOK + kb0 + 64 + soff;
        kr0 = *(const bf16x8*)(kp); kr1 = *(const bf16x8*)(kp + 8);
        vr0 = *(const bf16x8*)(vp); vr1 = *(const bf16x8*)(vp + 8);
    }
    __syncthreads();

    for (int it = 0; it < 16; ++it) {
        const int cur = it & 1;
        const __bf16* Kc = &lds[half][0][cur][0];
        const __bf16* Vc = &lds[half][1][cur][0];

        // ---- S^T = K·Q^T ----
        f32x16 s0, s1;
#pragma unroll
        for (int r = 0; r < 16; ++r) { s0[r] = 0.0f; s1[r] = 0.0f; }
#pragma unroll
        for (int st = 0; st < 4; ++st) {
            bf16x8 a0 = *(const bf16x8*)&Kc[(c32)      * 72 + h32 * 8 + st * 16];
            bf16x8 a1 = *(const bf16x8*)&Kc[(32 + c32) * 72 + h32 * 8 + st * 16];
            s0 = __builtin_amdgcn_mfma_f32_32x32x16_bf16(a0, qf[st], s0, 0, 0, 0);
            s1 = __builtin_amdgcn_mfma_f32_32x32x16_bf16(a1, qf[st], s1, 0, 0, 0);
        }

        // ---- fused per-ks: exp2 -> pack -> half-exchange -> PV ----
#pragma unroll
        for (int ks = 0; ks < 4; ++ks) {
            const f32x16& sv = (ks & 2) ? s1 : s0;
            const int rb = (ks & 1) * 8;
            float p0 = EXP2F(sv[rb + 0]), p1 = EXP2F(sv[rb + 1]);
            float p2 = EXP2F(sv[rb + 2]), p3 = EXP2F(sv[rb + 3]);
            float p4 = EXP2F(sv[rb + 4]), p5 = EXP2F(sv[rb + 5]);
            float p6 = EXP2F(sv[rb + 6]), p7 = EXP2F(sv[rb + 7]);
            lsum += ((p0 + p1) + (p2 + p3)) + ((p4 + p5) + (p6 + p7));
            unsigned A0 = pk2(p0, p1), A1 = pk2(p2, p3);
            unsigned B0 = pk2(p4, p5), B1 = pk2(p6, p7);
            unsigned s0w = h32 ? A0 : B0;
            unsigned s1w = h32 ? A1 : B1;
            unsigned r0 = __shfl_xor(s0w, 32, 64);
            unsigned r1 = __shfl_xor(s1w, 32, 64);
            FU fu;
            fu.u[0] = h32 ? r0 : A0;
            fu.u[1] = h32 ? r1 : A1;
            fu.u[2] = h32 ? B0 : r0;
            fu.u[3] = h32 ? B1 : r1;
            bf16x8 v0 = *(const bf16x8*)&Vc[(c32)      * 72 + h32 * 8 + ks * 16];
            bf16x8 v1 = *(const bf16x8*)&Vc[(32 + c32) * 72 + h32 * 8 + ks * 16];
            O[0] = __builtin_amdgcn_mfma_f32_32x32x16_bf16(v0, fu.v, O[0], 0, 0, 0);
            O[1] = __builtin_amdgcn_mfma_f32_32x32x16_bf16(v1, fu.v, O[1], 0, 0, 0);
        }

        // ---- stage tile it+1 (in regs) -> other buffer ----
        *(bf16x8*)&lds[half][0][cur ^ 1][rs * 72 + soff]     = kr0;
        *(bf16x8*)&lds[half][0][cur ^ 1][rs * 72 + soff + 8] = kr1;
        *(bf16x8*)&lds[half][1][cur ^ 1][rs * 72 + soff]     = vr0;
        *(bf16x8*)&lds[half][1][cur ^ 1][rs * 72 + soff + 8] = vr1;

        // ---- prefetch tile it+2 ----
        {
            int itn = (it + 2) & 15;
            const __bf16* kp = Kg  + base + (size_t)(kb0 + itn * 64 + rs) * 64 + soff;
            const __bf16* vp = Vtg + base + (size_t)rs * TTOK + kb0 + itn * 64 + soff;
            kr0 = *(const bf16x8*)(kp); kr1 = *(const bf16x8*)(kp + 8);
            vr0 = *(const bf16x8*)(vp); vr1 = *(const bf16x8*)(vp + 8);
        }

        // counted barrier: the 4 prefetch loads stay in flight (T4);
        // lgkmcnt(0) seals this tile's ds_reads + stage ds_writes.
        WB(4);
    }

    // ---- combine halves: waves 4-7 deposit partials, waves 0-3 merge ----
    // layout [qw][r][lane]: 64 consecutive floats per row -> conflict-free
    float* cb = (float*)&lds[0][0][0][0];   // 33 KB < 72 KB, post-barrier safe
    if (wave >= 4) {
        float* me = cb + qw * 2048;
#pragma unroll
        for (int r = 0; r < 16; ++r) {
            me[r * 64 + lane]        = O[0][r];
            me[(16 + r) * 64 + lane] = O[1][r];
        }
        cb[8192 + qw * 64 + lane] = lsum;
    }
    __syncthreads();
    if (wave >= 4) return;
    {
        const float* pr = cb + qw * 2048;
#pragma unroll
        for (int r = 0; r < 16; ++r) {
            O[0][r] += pr[r * 64 + lane];
            O[1][r] += pr[(16 + r) * 64 + lane];
        }
        lsum += cb[8192 + qw * 64 + lane];
    }
    const float ltot = lsum + __shfl_xor(lsum, 32, 64);
    const float inv  = 1.0f / ltot;

    // ---- vq: one-time coalesced global re-read of own-q V column ----
    const int q = q0 + qw * 32 + c32;
    float vq[2][16];
#pragma unroll
    for (int db = 0; db < 2; ++db)
#pragma unroll
        for (int rg = 0; rg < 16; ++rg) {
            int d = db * 32 + (rg & 3) + 8 * (rg >> 2) + 4 * h32;
            vq[db][rg] = (float)Vtg[base + (size_t)d * TTOK + q];
        }

    // ---- epilogue: Y = O/l ; exclusive output mod ; packed bf16 store ----
    const int b = bh >> 4, h = bh & 15;
    float y[2][16];
    float yv = 0.f, v2 = 0.f, yy = 0.f;
#pragma unroll
    for (int db = 0; db < 2; ++db)
#pragma unroll
        for (int rg = 0; rg < 16; ++rg) {
            float yval = O[db][rg] * inv;
            float vval = vq[db][rg];
            y[db][rg] = yval;
            yv += yval * vval; v2 += vval * vval; yy += yval * yval;
        }
    yv += __shfl_xor(yv, 32, 64);
    v2 += __shfl_xor(v2, 32, 64);
    yy += __shfl_xor(yy, 32, 64);
    float scl = (v2 > 0.0f) ? yv / fmaxf(v2, 1.1754943508222875e-38f) : 0.0f;
    float zz = 0.f;
    float zvv[2][16];
#pragma unroll
    for (int db = 0; db < 2; ++db)
#pragma unroll
        for (int rg = 0; rg < 16; ++rg) {
            zvv[db][rg] = y[db][rg] - scl * vq[db][rg];
            zz += zvv[db][rg] * zvv[db][rg];
        }
    zz += __shfl_xor(zz, 32, 64);
    float znorm = sqrtf(zz);
    float refn  = fmaxf(sqrtf(yy), sqrtf(v2));
    bool  wipe  = (v2 > 0.0f) && (znorm <= 1.1920928955078125e-07f * 64.0f * refn);
#pragma unroll
    for (int db = 0; db < 2; ++db)
#pragma unroll
        for (int g = 0; g < 4; ++g) {
            bf16x4 pk;
#pragma unroll
            for (int r = 0; r < 4; ++r)
                pk[r] = (__bf16)(wipe ? 0.0f : zvv[db][4 * g + r]);
            int d = db * 32 + 8 * g + 4 * h32;
            *(bf16x4*)&Zm[((size_t)(b * TTOK + q)) * DM + h * 64 + d] = pk;
        }
}

// =====================================================================
extern "C" void kernel_launch(void* const* d_in, const int* in_sizes, int n_in,
                              void* d_out, int out_size, void* d_ws, size_t ws_size,
                              hipStream_t stream) {
    const float* x  = (const float*)d_in[0];
    const float* Wq = (const float*)d_in[1];
    const float* Wk = (const float*)d_in[2];
    const float* Wv = (const float*)d_in[3];
    const float* Wo = (const float*)d_in[4];

    const size_t NX = (size_t)NTOK * DM;   // 4M
    const size_t NW = (size_t)DM * DM;     // 1M
    __bf16* xb  = (__bf16*)d_ws;
    __bf16* wqb = xb  + NX;
    __bf16* wkb = wqb + NW;
    __bf16* wvb = wkb + NW;
    __bf16* wob = wvb + NW;
    __bf16* Qb  = wob + NW;
    __bf16* Kb  = Qb  + NX;
    __bf16* Vtb = Kb  + NX;
    __bf16* Zmb = Vtb + NX;   // total 24M bf16 = 48 MB

    cvt_all<<<(NX + 4 * NW) / 2048, 256, 0, stream>>>(x, Wq, Wk, Wv, Wo, xb);

    // QKV: z0/z1 = Wq,Wk · x^T ; z2 = x · Wv^T  (LDS-transpose epilogues)
    gemm_qkv<<<dim3(32, 8, 3), 256, 0, stream>>>(
        xb, wqb, wkb, wvb, Qb, Kb, Vtb);

    // attn: 8-wave KV-split blocks (512 thr), 2 blocks/CU = 4 waves/SIMD
    attn_mfma<<<dim3(TTOK / 128, 32), 512, 0, stream>>>(Qb, Kb, Vtb, Zmb);

    // out = Zm · Wo^T (BM=64 x BN=128, 512 blocks = 2/CU, XCD-swizzled)
    gemm_oproj<<<dim3(8, 64), 256, 0, stream>>>(Zmb, wob, (float*)d_out);
}